// Round 7
// baseline (355.504 us; speedup 1.0000x reference)
//
#include <hip/hip_runtime.h>
#include <hip/hip_cooperative_groups.h>
#include <stdint.h>

namespace cg = cooperative_groups;

#define KPS 512
#define NBOX 1536
#define NBINS 1024
#define CAP 96          // bucket capacity; bins >= cutoff hold <= ~30 keys (3x margin)

// scale cell counts: 32*H*H*3
#define S13 16224
#define S26 64896
#define S52 259584
#define TOTCELL 340704

__device__ __forceinline__ uint32_t f2u(float x){ union{float f;uint32_t u;}v; v.f=x; return v.u; }
__device__ __forceinline__ float u2f(uint32_t x){ union{float f;uint32_t u;}v; v.u=x; return v.f; }

__device__ __forceinline__ int binOf(float s){
    int b = (int)((s - 0.6f) * 2560.0f);    // 1024 bins over (0.6, 1.0)
    if (b < 0) b = 0;
    if (b > NBINS-1) b = NBINS-1;
    return b;
}

__device__ __forceinline__ unsigned long long readlane64(unsigned long long v, int i){
    unsigned lo = (unsigned)__builtin_amdgcn_readlane((int)(unsigned)v, i);
    unsigned hi = (unsigned)__builtin_amdgcn_readlane((int)(unsigned)(v >> 32), i);
    return ((unsigned long long)hi << 32) | (unsigned long long)lo;
}

// ONE cooperative kernel = entire pipeline. 256 blocks x 1024 threads
// (<=1 block/CU guaranteed co-resident). grid.sync() replaces the 5 kernel
// boundaries -> zero dispatch serialization. Phase math is byte-identical
// to the verified R6 pipeline.
__global__ void __launch_bounds__(1024) k_mega(
        const float* __restrict__ o13, const float* __restrict__ o26,
        const float* __restrict__ o52,
        const float* __restrict__ a13, const float* __restrict__ a26,
        const float* __restrict__ a52,
        unsigned long long* __restrict__ bucket, int* __restrict__ hist,
        int* __restrict__ cnt, unsigned long long* __restrict__ sel,
        float* __restrict__ sboxes, unsigned long long* __restrict__ vwords,
        unsigned long long* __restrict__ diagR, unsigned* __restrict__ Tcol,
        float* __restrict__ out){
    cg::grid_group grid = cg::this_grid();
    int t  = threadIdx.x;
    int blk = blockIdx.x;
    int nb  = gridDim.x;
    int gtid = blk*1024 + t;
    int nth  = nb*1024;

    __shared__ union {
        struct { int suf[NBINS]; unsigned long long un[640]; int sB; } sf;   // selfin
        unsigned long long sk[NBOX];                                          // decode stage
        struct { unsigned long long keepw[24]; unsigned partial[2][4][64]; } nm; // nms
    } sh;

    // ---- P0: zero hist ----
    for (int id = gtid; id < 3*NBINS; id += nth) hist[id] = 0;
    grid.sync();

    // ---- P1: score + direct bucket binning (hist atomicAdd = bucket cursor) ----
    for (int id = gtid; id < TOTCELL; id += nth){
        int scale, idl, H;
        const float* src;
        if (id < S13)            { scale=0; idl=id;            H=13; src=o13; }
        else if (id < S13+S26)   { scale=1; idl=id-S13;        H=26; src=o26; }
        else                     { scale=2; idl=id-(S13+S26);  H=52; src=o52; }
        int HW = H*H;
        int p  = idl / HW;          // plane-major mapping for coalescing
        int hw = idl - p*HW;
        int n  = p / 3;
        int a  = p - n*3;
        float x = src[(size_t)(n*255 + a*85)*HW + hw];
        float s = (float)(1.0 / (1.0 + exp(-(double)x)));   // correctly-rounded f32 sigmoid
        if (s > 0.6f){
            int cidx = (n*HW + hw)*3 + a;
            unsigned long long key = ((unsigned long long)f2u(s) << 20)
                | ((unsigned long long)(2-scale) << 18)
                | (unsigned long long)(262143 - cidx);
            int slot = scale*NBINS + binOf(s);
            int pos = atomicAdd(&hist[slot], 1);
            if (pos < CAP) bucket[(size_t)slot*CAP + pos] = key;
        }
    }
    grid.sync();

    // ---- P2: cutoff + gather + rank-sort (blocks 0..2, one per scale) ----
    if (blk < 3){
        int s = blk;
        int h = hist[s*NBINS + t];
        sh.sf.suf[t] = h; __syncthreads();
        for (int d = 1; d < NBINS; d <<= 1){        // in-place suffix scan
            int v = (t + d < NBINS) ? sh.sf.suf[t + d] : 0;
            __syncthreads();
            sh.sf.suf[t] += v;
            __syncthreads();
        }
        int total = sh.sf.suf[0];
        int A = (t < NBINS-1) ? sh.sf.suf[t+1] : 0;   // count strictly above bin t
        if (t == 0 && total < KPS) sh.sf.sB = -1;
        if (A < KPS && A + h >= KPS) sh.sf.sB = t;    // unique crossing when total>=KPS
        __syncthreads();
        int B = sh.sf.sB;
        int Bg = (B < 0) ? 0 : B;
        if (t + Bg < NBINS){
            int b = Bg + t;
            int cb = hist[s*NBINS + b]; if (cb > CAP) cb = CAP;
            int off = (b == NBINS-1) ? 0 : sh.sf.suf[b+1];
            for (int e = 0; e < cb; e++)
                sh.sf.un[off + e] = bucket[(size_t)(s*NBINS + b)*CAP + e];
        }
        __syncthreads();
        int hB = hist[s*NBINS + Bg]; if (hB > CAP) hB = CAP;
        int E = ((Bg == NBINS-1) ? 0 : sh.sf.suf[Bg+1]) + hB;   // gathered count
        int Nsel = (E < KPS) ? E : KPS;
        for (int e = t; e < E; e += 1024){
            unsigned long long k = sh.sf.un[e];
            int rank = 0;
            for (int q = 0; q < E; q++) rank += (sh.sf.un[q] > k) ? 1 : 0;
            if (rank < Nsel) sel[s*KPS + rank] = k;
        }
        if (t < KPS && t >= Nsel) sel[s*KPS + t] = 0ull;   // sentinels
        if (t == 0) cnt[s] = Nsel;
    }
    grid.sync();

    // ---- P3: decode + merge-by-rank (blocks 0..95, one wave per box) ----
    if (blk < NBOX/16){
        for (int r = t; r < NBOX; r += 1024) sh.sk[r] = sel[r];
        __syncthreads();
        int wv = t >> 6, lane = t & 63;
        int b = blk*16 + wv;                 // [0, 1536)
        unsigned long long key = sh.sk[b];
        int pc = 0;
        for (int q = lane; q < NBOX; q += 64){
            unsigned long long kq = sh.sk[q];
            pc += (kq > key || (kq == key && q < b)) ? 1 : 0;
        }
        #pragma unroll
        for (int off = 32; off; off >>= 1) pc += __shfl_xor(pc, off);
        int rank = pc;                       // permutation of [0,NBOX)
        float* row = sboxes + rank*12;
        if ((key >> 20) == 0ull){            // sentinel
            if (lane < 9) row[lane] = 0.f;
        } else {
            int scale = 2 - (int)((key >> 18) & 3ull);
            int cidx  = 262143 - (int)(key & 0x3FFFFull);
            uint32_t sbits = (uint32_t)(key >> 20);
            const float* src; const float* anch; int H; float tt;
            if (scale == 0){ src=o13; anch=a13; H=13; tt=32.f; }
            else if (scale == 1){ src=o26; anch=a26; H=26; tt=16.f; }
            else { src=o52; anch=a52; H=52; tt=8.f; }
            int HW = H*H;
            int a  = cidx % 3;
            int hw = (cidx/3) % HW;
            int n  = cidx / (3*HW);
            int hh = hw / H;
            int ww = hw - hh*H;
            const float* cellbase = src + (size_t)(n*255 + a*85)*HW + hw;
            // argmax over 80 classes, tie -> lowest class index
            float bv = cellbase[(size_t)(5 + lane)*HW];
            int bi = lane;
            if (lane < 16){
                float v2 = cellbase[(size_t)(69 + lane)*HW];
                if (v2 > bv){ bv = v2; bi = 64 + lane; }
            }
            #pragma unroll
            for (int off=32; off; off>>=1){
                float vo = __shfl_xor(bv, off);
                int io = __shfl_xor(bi, off);
                if (vo > bv || (vo == bv && io < bi)){ bv = vo; bi = io; }
            }
            if (lane == 0){
                float v1 = cellbase[(size_t)1*HW];
                float v2 = cellbase[(size_t)2*HW];
                float v3 = cellbase[(size_t)3*HW];
                float v4 = cellbase[(size_t)4*HW];
                float cx = ((float)ww + v1) * tt / 416.0f;
                float cy = ((float)hh + v2) * tt / 416.0f;
                float e3 = (float)exp((double)v3);
                float e4 = (float)exp((double)v4);
                float bw = anch[a*2+0] * e3 / 416.0f;
                float bh = anch[a*2+1] * e4 / 416.0f;
                row[0] = (float)n;  row[1] = cx; row[2] = cy; row[3] = bw; row[4] = bh;
                row[5] = u2f(sbits); row[6] = (float)bi; row[7] = (float)hh; row[8] = (float)ww;
            }
        }
        if (blk == 0 && t < 24){
            int nv = cnt[0] + cnt[1] + cnt[2];   // valid keys sort to a contiguous prefix
            int rem = nv - t*64;
            vwords[t] = rem >= 64 ? ~0ull : (rem <= 0 ? 0ull : ((1ull << rem) - 1ull));
        }
    }
    grid.sync();

    // ---- P4: suppression masks (blocks 0..95, one wave per row) ----
    if (blk < NBOX/16){
        int wv = t >> 6, lane = t & 63;
        int i = blk*16 + wv;                 // [0, 1536)
        int gi = i >> 6;
        float cxi = sboxes[i*12+1], cyi = sboxes[i*12+2], wi = sboxes[i*12+3], hi = sboxes[i*12+4];
        float x1i = cxi - wi/2.0f, y1i = cyi - hi/2.0f, x2i = cxi + wi/2.0f, y2i = cyi + hi/2.0f;
        float ari = fmaxf(x2i-x1i, 0.f) * fmaxf(y2i-y1i, 0.f);
        unsigned colbits = 0u;
        for (int c=0; c<24; c++){
            int j = c*64 + lane;
            float cxj = sboxes[j*12+1], cyj = sboxes[j*12+2], wj = sboxes[j*12+3], hj = sboxes[j*12+4];
            float x1j = cxj - wj/2.0f, y1j = cyj - hj/2.0f, x2j = cxj + wj/2.0f, y2j = cyj + hj/2.0f;
            float arj = fmaxf(x2j-x1j, 0.f) * fmaxf(y2j-y1j, 0.f);
            float ix = fmaxf(0.f, fminf(x2i, x2j) - fmaxf(x1i, x1j));
            float iy = fmaxf(0.f, fminf(y2i, y2j) - fmaxf(y1i, y1j));
            float inter = ix * iy;
            float iou = inter / fmaxf(fminf(ari, arj), 1e-9f);
            bool sb = (iou > 0.7f) && (j > i);
            colbits |= sb ? (1u << c) : 0u;
        }
        Tcol[(size_t)i*64 + lane] = colbits;
        unsigned long long rowbits = __ballot(((colbits >> gi) & 1u) != 0u);
        if (lane == 0) diagR[i] = rowbits;
    }
    grid.sync();

    // ---- P5: greedy NMS + output (block 0; waves 0-3 active, 4-15 sync-only) ----
    if (blk == 0){
        int wv = t >> 6, lane = t & 63;
        bool act = (wv < 4);
        unsigned SS = 0u;
        unsigned long long rowR = diagR[lane];
        unsigned long long vcur = vwords[0];
        unsigned rows[16];
        if (act){
            const unsigned* b0 = Tcol + (size_t)(wv*16)*64 + lane;
            #pragma unroll
            for (int i=0;i<16;i++) rows[i] = b0[i*64];
        }
        for (int g = 0; g < 24; g++){
            unsigned long long Rnext = 0ull, vnext = 0ull;
            if (act && g < 23){
                Rnext = diagR[(g+1)*64 + lane];
                vnext = vwords[g+1];
            }
            if (act){
                bool live = (((vcur >> lane) & 1ull) != 0ull) && (((SS >> g) & 1u) == 0u);
                unsigned long long pend = __ballot(live);
                unsigned long long Z = __ballot(live && ((rowR & pend) != 0ull));
                unsigned long long kept = pend;
                unsigned long long iter = Z;
                while (iter){
                    int i = __ffsll((long long)iter) - 1;
                    iter &= iter - 1ull;
                    if ((kept >> i) & 1ull){
                        unsigned long long sup = readlane64(rowR, i);   // only bits > i
                        kept &= ~sup;
                        iter &= ~sup;
                    }
                }
                if (t == 0) sh.nm.keepw[g] = kept;
                unsigned kbits = (unsigned)((kept >> (wv*16)) & 0xFFFFull);   // wave-uniform
                unsigned acc = 0u;
                #pragma unroll
                for (int i=0;i<16;i++) acc |= (0u - ((kbits >> i) & 1u)) & rows[i];
                if (g < 23){
                    const unsigned* nbp = Tcol + (size_t)((g+1)*64 + wv*16)*64 + lane;
                    #pragma unroll
                    for (int i=0;i<16;i++) rows[i] = nbp[i*64];
                }
                sh.nm.partial[g & 1][wv][lane] = acc;
            }
            __syncthreads();
            if (act){
                SS |= sh.nm.partial[g & 1][0][lane] | sh.nm.partial[g & 1][1][lane]
                    | sh.nm.partial[g & 1][2][lane] | sh.nm.partial[g & 1][3][lane];
            }
            rowR = Rnext; vcur = vnext;
        }
        for (int e=t; e<NBOX*9; e+=1024){
            int r = e / 9;
            int c = e - r*9;
            bool kp = ((sh.nm.keepw[r >> 6] >> (r & 63)) & 1ull) != 0ull;
            out[e] = kp ? sboxes[r*12 + c] : 0.f;
        }
    }
}

extern "C" void kernel_launch(void* const* d_in, const int* in_sizes, int n_in,
                              void* d_out, int out_size, void* d_ws, size_t ws_size,
                              hipStream_t stream){
    const float* o13 = (const float*)d_in[0];
    const float* o26 = (const float*)d_in[1];
    const float* o52 = (const float*)d_in[2];
    const float* a13 = (const float*)d_in[3];
    const float* a26 = (const float*)d_in[4];
    const float* a52 = (const float*)d_in[5];
    char* ws = (char*)d_ws;
    unsigned long long* bucket = (unsigned long long*)(ws);             // 3*1024*96*8 = 2,359,296
    unsigned* Tcol            = (unsigned*)(ws);                        // 393,216 — ALIASES bucket (dead after P2)
    int* hist                 = (int*)(ws + 2359296);                   // 12,288
    int* cnt                  = (int*)(ws + 2371584);                   // 128
    unsigned long long* sel   = (unsigned long long*)(ws + 2371712);    // 12,288
    float* sboxes             = (float*)(ws + 2384000);                 // 73,728
    unsigned long long* vw    = (unsigned long long*)(ws + 2457728);    // 256
    unsigned long long* diagR = (unsigned long long*)(ws + 2457984);    // 12,288 (end ~2.47 MB)
    float* out = (float*)d_out;

    void* args[] = { (void*)&o13, (void*)&o26, (void*)&o52,
                     (void*)&a13, (void*)&a26, (void*)&a52,
                     (void*)&bucket, (void*)&hist, (void*)&cnt, (void*)&sel,
                     (void*)&sboxes, (void*)&vw, (void*)&diagR, (void*)&Tcol,
                     (void*)&out };
    hipLaunchCooperativeKernel((const void*)k_mega, dim3(256), dim3(1024),
                               args, 0, stream);
}